// Round 2
// baseline (152.983 us; speedup 1.0000x reference)
//
#include <hip/hip_runtime.h>
#include <math.h>

// Problem constants
#define B_  4
#define S_  1024
#define D_  1024
#define H_  16
#define DK_ 64
#define M_  (B_ * S_)   // 4096 rows for the K GEMM

typedef __bf16 bf16x8 __attribute__((ext_vector_type(8)));
typedef float  f32x4  __attribute__((ext_vector_type(4)));

// ---- bf16 helpers (RNE) ----------------------------------------------------
__device__ __forceinline__ unsigned short f2bf(float f) {
  unsigned u = __builtin_bit_cast(unsigned, f);
  u = (u + 0x7FFFu + ((u >> 16) & 1u)) >> 16;
  return (unsigned short)u;
}
__device__ __forceinline__ float bf2f(unsigned short h) {
  unsigned u = ((unsigned)h) << 16;
  return __builtin_bit_cast(float, u);
}

// async global->LDS, 16 B per lane; LDS dest = wave-uniform base + lane*16
__device__ __forceinline__ void gl_lds16(const void* g, void* lds) {
  __builtin_amdgcn_global_load_lds(
      (const __attribute__((address_space(1))) unsigned int*)(unsigned long long)g,
      (__attribute__((address_space(3))) unsigned int*)(unsigned int)(unsigned long long)lds,
      16, 0, 0);
}

// ---------------------------------------------------------------------------
// PREP (round-14): only what the fusion GEMM launch reads.
//  blocks [   0, 512): W_G fp32 -> bf16 cast (row-major, BT operand of fusion)
//  blocks [ 512,1536): Wk transpose+cast -> WkT bf16 [n][mid]
//  blocks [1536,1664): g0 partials (fp32): partG[(sg*4+b)*1024+mid] =
//                      sum_{k in sg-slab} X[b,0,k]*W_G[k,mid]
//  blocks [1664,1792): biasK partials: partB[sl*1024+n] =
//                      sum_{mid in sl-slab} b_G[mid]*Wk[mid,n]
// (X bf16 cast and RoPE table moved into the fusion launch — their consumers
//  are the K-GEMM launch, so they overlap the latency-bound fusion GEMM.)
// ---------------------------------------------------------------------------
__global__ __launch_bounds__(256) void prep_kernel(
    const float* __restrict__ X, const float* __restrict__ W_G,
    const float* __restrict__ Wk, const float* __restrict__ bG,
    unsigned short* __restrict__ WGbf, unsigned short* __restrict__ WkT,
    float* __restrict__ partG, float* __restrict__ partB) {
  __shared__ float tle[32][33];
  __shared__ float gs2[4][32];
  __shared__ float bgs[32];
  const int blk = blockIdx.x;
  const int tid = threadIdx.x;

  if (blk < 512) {
    // W_G plain cast (1M elems over 512 blocks)
    const int i = (blk * 256 + tid) * 2;
    const float4 v0 = ((const float4*)W_G)[i];
    const float4 v1 = ((const float4*)W_G)[i + 1];
    ushort4 h0, h1;
    h0.x = f2bf(v0.x); h0.y = f2bf(v0.y); h0.z = f2bf(v0.z); h0.w = f2bf(v0.w);
    h1.x = f2bf(v1.x); h1.y = f2bf(v1.y); h1.z = f2bf(v1.z); h1.w = f2bf(v1.w);
    ((ushort4*)WGbf)[i] = h0;
    ((ushort4*)WGbf)[i + 1] = h1;
  } else if (blk < 1536) {
    // Wk transpose+cast (32x32 tiles, LDS bounce)
    const int t = blk - 512;
    const int k0 = (t & 31) * 32;
    const int n0 = (t >> 5) * 32;
    const int tx = tid & 31;
    const int ty = tid >> 5;  // 0..7
#pragma unroll
    for (int r = 0; r < 32; r += 8)
      tle[ty + r][tx] = Wk[(size_t)(k0 + ty + r) * 1024 + n0 + tx];
    __syncthreads();
#pragma unroll
    for (int r = 0; r < 32; r += 8)
      WkT[(size_t)(n0 + ty + r) * 1024 + k0 + tx] = f2bf(tle[tx][ty + r]);
  } else if (blk < 1664) {
    // g0 partials: fp32, reads X row 0 of each batch + a W_G slab
    const int bl = blk - 1536;       // 0..127
    const int sg = bl >> 2;          // k-slab 0..31
    const int mg = bl & 3;           // mid group 0..3
    if (tid < 128) {
      const int b = tid >> 5, kk = tid & 31;
      gs2[b][kk] = X[(size_t)b * S_ * D_ + sg * 32 + kk];
    }
    __syncthreads();
    const int mid = mg * 256 + tid;
    float a0 = 0.f, a1 = 0.f, a2 = 0.f, a3 = 0.f;
#pragma unroll
    for (int kk = 0; kk < 32; ++kk) {
      const float w = W_G[(size_t)(sg * 32 + kk) * 1024 + mid];
      a0 = fmaf(gs2[0][kk], w, a0);
      a1 = fmaf(gs2[1][kk], w, a1);
      a2 = fmaf(gs2[2][kk], w, a2);
      a3 = fmaf(gs2[3][kk], w, a3);
    }
    partG[(size_t)(sg * 4 + 0) * 1024 + mid] = a0;
    partG[(size_t)(sg * 4 + 1) * 1024 + mid] = a1;
    partG[(size_t)(sg * 4 + 2) * 1024 + mid] = a2;
    partG[(size_t)(sg * 4 + 3) * 1024 + mid] = a3;
  } else {
    // biasK partials: partB[sl][n] = sum_{mid in slab} b_G[mid]*Wk[mid][n]
    const int bl = blk - 1664;       // 0..127
    const int sl = bl >> 2;          // mid-slab 0..31
    const int ng = bl & 3;
    if (tid < 32) bgs[tid] = bG[sl * 32 + tid];
    __syncthreads();
    const int n = ng * 256 + tid;
    float a = 0.f;
#pragma unroll
    for (int kk = 0; kk < 32; ++kk)
      a = fmaf(bgs[kk], Wk[(size_t)(sl * 32 + kk) * 1024 + n], a);
    partB[(size_t)sl * 1024 + n] = a;
  }
}

// ---------------------------------------------------------------------------
// bf16 MFMA GEMM — proven inner loop untouched. Round-14 changes:
//  * score mode (scores != nullptr): instead of writing C = K to global, the
//    epilogue folds RoPE into per-lane coefficients of the fp32 accumulator
//    (qw0 == q0 since position-0 rotation is identity) and produces
//    scores[b,h,s] plus per-chunk softmax partials mS directly.
//    Each block's 64 M-rows x 128 N-cols == 2 chunks x 2 heads, aligned.
//  * fusion launch extra blocks: q0 partials, biasK combine, RoPE table,
//    X fp32->bf16 cast (co-scheduled with the 128-block fusion GEMM).
// ---------------------------------------------------------------------------
#define GM 64
#define GN 128

__global__ __launch_bounds__(256) void gemm_bf16(
    const unsigned short* __restrict__ A, const unsigned short* __restrict__ BT,
    const float* __restrict__ bias, unsigned short* __restrict__ C,
    const int mShift, const int nGemmBlocks,
    const float* __restrict__ Wq, float* __restrict__ part,
    const float* __restrict__ partG, const float* __restrict__ bG,
    const float* __restrict__ partB, const float* __restrict__ bk,
    float* __restrict__ biasK,
    const float* __restrict__ X, unsigned short* __restrict__ Xbf,
    float* __restrict__ tab,
    const float* __restrict__ bq, const int* __restrict__ mask,
    float* __restrict__ scores, float* __restrict__ mS) {
  __shared__ __align__(16) unsigned short As[2][GM * 32];   // 8 KB
  __shared__ __align__(16) unsigned short Bs[2][GN * 32];   // 16 KB
  __shared__ float gs[4][32];
  __shared__ float q0s[128];
  __shared__ float sc[64][9];   // [s_loc][wv*2+ni], +1 pad col

  const int flat = blockIdx.x;
  const int tid  = threadIdx.x;

  if (flat >= nGemmBlocks) {
    const int eb = flat - nGemmBlocks;
    if (eb < 128) {
      // ---- fused q0 partial: part[(slab*4+b)*D+n] = sum_k g0[b,k]*Wq[k,n]
      const int slab = eb >> 2;            // 0..31 (k-slab of q0 GEMV)
      const int n = (eb & 3) * 256 + tid;  // 0..1023
      if (tid < 128) {
        const int b = tid >> 5, kk = tid & 31;
        float v = bG[slab * 32 + kk];
        const float* pg = partG + (size_t)b * 1024 + slab * 32 + kk;
#pragma unroll
        for (int sg = 0; sg < 32; ++sg) v += pg[(size_t)sg * 4096];
        gs[b][kk] = v;
      }
      __syncthreads();
      float a0 = 0.f, a1 = 0.f, a2 = 0.f, a3 = 0.f;
#pragma unroll
      for (int kk = 0; kk < 32; ++kk) {
        const float w = Wq[(size_t)(slab * 32 + kk) * D_ + n];
        a0 = fmaf(gs[0][kk], w, a0);
        a1 = fmaf(gs[1][kk], w, a1);
        a2 = fmaf(gs[2][kk], w, a2);
        a3 = fmaf(gs[3][kk], w, a3);
      }
      part[(size_t)(slab * 4 + 0) * D_ + n] = a0;
      part[(size_t)(slab * 4 + 1) * D_ + n] = a1;
      part[(size_t)(slab * 4 + 2) * D_ + n] = a2;
      part[(size_t)(slab * 4 + 3) * D_ + n] = a3;
    } else if (eb < 132) {
      // ---- biasK combine: biasK[n] = bk[n] + sum_sl partB[sl][n]
      const int n = (eb - 128) * 256 + tid;
      float v = bk[n];
#pragma unroll
      for (int sl = 0; sl < 32; ++sl) v += partB[(size_t)sl * 1024 + n];
      biasK[n] = v;
    } else if (eb < 260) {
      // ---- RoPE table: tab[s*64+2j]=cos(s*inv_j), +1 = sin
      const int idx = (eb - 132) * 256 + tid;
      const int s = idx >> 5, j = idx & 31;
      const float inv = (float)exp(-(double)j * (9.210340371976182736 / 32.0));
      float sn, c;
      sincosf((float)s * inv, &sn, &c);
      tab[(size_t)s * 64 + 2 * j] = c;
      tab[(size_t)s * 64 + 2 * j + 1] = sn;
    } else {
      // ---- X fp32 -> bf16 cast (consumer is the NEXT launch)
      const int i = ((eb - 260) * 256 + tid) * 2;  // float4 index
      const float4 v0 = ((const float4*)X)[i];
      const float4 v1 = ((const float4*)X)[i + 1];
      ushort4 h0, h1;
      h0.x = f2bf(v0.x); h0.y = f2bf(v0.y); h0.z = f2bf(v0.z); h0.w = f2bf(v0.w);
      h1.x = f2bf(v1.x); h1.y = f2bf(v1.y); h1.z = f2bf(v1.z); h1.w = f2bf(v1.w);
      ((ushort4*)Xbf)[i] = h0;
      ((ushort4*)Xbf)[i + 1] = h1;
    }
    return;
  }

  // ---- GEMM path ----
  const int bx = flat >> mShift;               // N tiles: 8
  const int by = flat & ((1 << mShift) - 1);   // M tiles: 16 or 64
  const int wv   = tid >> 6;
  const int lane = tid & 63;
  const int m0 = by * GM;
  const int n0 = bx * GN;

  // score mode: stage q0 (both heads of this block) into LDS before the loop;
  // covered by the loop's first __syncthreads.
  if (scores && tid < 128) {
    const int nq = n0 + tid;
    float v = bq[nq];
#pragma unroll
    for (int sl2 = 0; sl2 < 32; ++sl2)
      v += part[(size_t)(sl2 * 4 + (m0 >> 10)) * D_ + nq];
    q0s[tid] = v;
  }

  const int colOff = (lane & 3) * 8;
  const size_t aOff  = (size_t)(m0 + 16 * wv + (lane >> 2)) * 1024 + colOff;
  const size_t bOff0 = (size_t)(n0 + 32 * wv + (lane >> 2)) * 1024 + colOff;
  const size_t bOff1 = bOff0 + (size_t)16 * 1024;

  const int l15  = lane & 15;
  const int quad = lane >> 4;

  f32x4 acc[4][2];
#pragma unroll
  for (int i = 0; i < 4; ++i)
#pragma unroll
    for (int j = 0; j < 2; ++j) acc[i][j] = (f32x4){0.f, 0.f, 0.f, 0.f};

#pragma unroll 1
  for (int k0 = 0; k0 < 1024; k0 += 64) {
    __syncthreads();                      // prior LDS reads done
#pragma unroll
    for (int ks = 0; ks < 2; ++ks) {
      gl_lds16(A  + aOff  + k0 + ks * 32, &As[ks][wv * 512]);
      gl_lds16(BT + bOff0 + k0 + ks * 32, &Bs[ks][wv * 1024]);
      gl_lds16(BT + bOff1 + k0 + ks * 32, &Bs[ks][wv * 1024 + 512]);
    }
    __syncthreads();                      // vmcnt drain: LDS writes visible

#pragma unroll
    for (int ks = 0; ks < 2; ++ks) {
      bf16x8 af[4], bfr[2];
#pragma unroll
      for (int mi = 0; mi < 4; ++mi)
        af[mi] = *(const bf16x8*)(&As[ks][(mi * 16 + l15) * 32 + quad * 8]);
#pragma unroll
      for (int ni = 0; ni < 2; ++ni)
        bfr[ni] =
            *(const bf16x8*)(&Bs[ks][(wv * 32 + ni * 16 + l15) * 32 + quad * 8]);
#pragma unroll
      for (int mi = 0; mi < 4; ++mi)
#pragma unroll
        for (int ni = 0; ni < 2; ++ni)
          acc[mi][ni] = __builtin_amdgcn_mfma_f32_16x16x32_bf16(
              af[mi], bfr[ni], acc[mi][ni], 0, 0, 0);
    }
  }

  if (scores) {
    // ---- fused RoPE + q0-dot + per-chunk softmax-partial epilogue ----
    // K[s,n] = acc + biasK[n] (fp32, never materialized).
    // score[s] += K[s,n]*coef(s,n):
    //   coef(even d) = q0[d]*cos + q0[d+1]*sin
    //   coef(odd  d) = q0[d]*cos - q0[d-1]*sin
    const int b_i   = m0 >> 10;
    const int sbase = m0 & 1023;
#pragma unroll
    for (int ni = 0; ni < 2; ++ni) {
      const int n_loc = wv * 32 + ni * 16 + l15;  // 0..127
      const float bv  = bias[n0 + n_loc];
      const float q0a = q0s[n_loc];
      const float q0b = q0s[n_loc ^ 1];
      const float sq  = (n_loc & 1) ? -q0b : q0b;
      const int j2    = (n_loc & 63) & ~1;
#pragma unroll
      for (int mi = 0; mi < 4; ++mi) {
#pragma unroll
        for (int r = 0; r < 4; ++r) {
          const int s_loc = mi * 16 + quad * 4 + r;
          const float2 cs =
              *(const float2*)(tab + (size_t)(sbase + s_loc) * 64 + j2);
          const float coef = q0a * cs.x + sq * cs.y;
          float v = (acc[mi][ni][r] + bv) * coef;
          v += __shfl_xor(v, 1);
          v += __shfl_xor(v, 2);
          v += __shfl_xor(v, 4);
          v += __shfl_xor(v, 8);   // sum over 16 lanes (same quad = same s)
          if (l15 == 0) sc[s_loc][wv * 2 + ni] = v;
        }
      }
    }
    __syncthreads();
    if (tid < 128) {
      const int h_loc = tid >> 6;   // wave0 = head0, wave1 = head1
      const int s_loc = tid & 63;
      const float* row = sc[s_loc];
      float dot = (row[h_loc * 4 + 0] + row[h_loc * 4 + 1]) +
                  (row[h_loc * 4 + 2] + row[h_loc * 4 + 3]);
      dot *= 0.125f;  // 1/sqrt(64)
      const int s = sbase + s_loc;
      if (mask[b_i * S_ + s] == 0) dot = -1e9f;
      const int bh = b_i * H_ + (bx * 2 + h_loc);
      scores[(size_t)bh * S_ + s] = dot;
      float mx = dot;
#pragma unroll
      for (int off = 16; off >= 1; off >>= 1)
        mx = fmaxf(mx, __shfl_xor(mx, off, 32));
      float e = expf(dot - mx);
#pragma unroll
      for (int off = 16; off >= 1; off >>= 1) e += __shfl_xor(e, off, 32);
      if ((s_loc & 31) == 0) {
        const int ch = ((by & 15) << 1) + (s_loc >> 5);
        mS[((size_t)bh * 32 + ch) * 2 + 0] = mx;
        mS[((size_t)bh * 32 + ch) * 2 + 1] = e;
      }
    }
    return;
  }

  // epilogue: C/D layout col = lane&15, row = quad*4 + r (m89/m91 verified)
#pragma unroll
  for (int ni = 0; ni < 2; ++ni) {
    const int n = n0 + wv * 32 + ni * 16 + l15;
    const float bv = bias ? bias[n] : 0.f;
#pragma unroll
    for (int mi = 0; mi < 4; ++mi) {
#pragma unroll
      for (int r = 0; r < 4; ++r) {
        const int m = m0 + mi * 16 + quad * 4 + r;
        C[(size_t)m * 1024 + n] = f2bf(acc[mi][ni][r] + bv);
      }
    }
  }
}

// ---------------------------------------------------------------------------
// Conv1d (16->1024, k=3, pad=1) + bias + ReLU — round-12 v3 verbatim.
// ---------------------------------------------------------------------------
__global__ __launch_bounds__(256) void conv_norm_relu_kernel(
    const float* __restrict__ scores, const float* __restrict__ mS,
    const float* __restrict__ cw, const float* __restrict__ cb,
    float* __restrict__ out) {
  const int b  = blockIdx.y;
  const int s0 = blockIdx.x * 128;
  const int o0 = blockIdx.z * 128;
  const int tid = threadIdx.x;
  const int tx = tid & 15;   // s group: s = s0 + tx*8 + j
  const int ty = tid >> 4;   // o group: o = o0 + ty*8 + i

  __shared__ float msh[16], ish[16];
  __shared__ __align__(16) float wT[48][128];  // transposed weights, 24 KB
  __shared__ float cbs[128];
  __shared__ __align__(16) float pm[16][132];  // p, row stride 132 (16B-align)

  // softmax combine (round-6 proven)
  if (tid < 16) {
    const int bh = b * H_ + tid;
    float m = -3e38f;
#pragma unroll
    for (int c = 0; c < 32; ++c)
      m = fmaxf(m, mS[(size_t)(bh * 32 + c) * 2]);
    float S = 0.f;
#pragma unroll
    for (int c = 0; c < 32; ++c)
      S += mS[(size_t)(bh * 32 + c) * 2 + 1] *
           expf(mS[(size_t)(bh * 32 + c) * 2] - m);
    msh[tid] = m;
    ish[tid] = 1.f / S;
  }
  // weight tile, transposed: wT[ct][ol] = cw[(o0+ol)*48 + ct]
  for (int i = tid; i < 128 * 48; i += 256) {
    const int ol = i / 48, ct = i % 48;
    wT[ct][ol] = cw[(size_t)(o0 + ol) * 48 + ct];
  }
  if (tid < 128) cbs[tid] = cb[o0 + tid];
  __syncthreads();  // msh/ish ready

  // p halo: pm[c][ss] = p(b, c, s0-1+ss), ss in [0,130)
  for (int i = tid; i < 16 * 130; i += 256) {
    const int c = i / 130, ss = i % 130;
    const int gs = s0 - 1 + ss;
    pm[c][ss] = (gs >= 0 && gs < S_)
                    ? expf(scores[(size_t)(b * H_ + c) * S_ + gs] - msh[c]) *
                          ish[c]
                    : 0.f;
  }
  __syncthreads();

  float acc[8][8];
#pragma unroll
  for (int i = 0; i < 8; ++i) {
    const float cv = cbs[ty * 8 + i];
#pragma unroll
    for (int j = 0; j < 8; ++j) acc[i][j] = cv;
  }

#pragma unroll
  for (int c = 0; c < 16; ++c) {
    float p[12];
    *(float4*)(p + 0) = *(const float4*)&pm[c][tx * 8 + 0];
    *(float4*)(p + 4) = *(const float4*)&pm[c][tx * 8 + 4];
    *(float4*)(p + 8) = *(const float4*)&pm[c][tx * 8 + 8];
#pragma unroll
    for (int t = 0; t < 3; ++t) {
      float w[8];
      *(float4*)(w + 0) = *(const float4*)&wT[c * 3 + t][ty * 8 + 0];
      *(float4*)(w + 4) = *(const float4*)&wT[c * 3 + t][ty * 8 + 4];
#pragma unroll
      for (int i = 0; i < 8; ++i)
#pragma unroll
        for (int j = 0; j < 8; ++j)
          acc[i][j] = fmaf(p[j + t], w[i], acc[i][j]);
    }
  }

#pragma unroll
  for (int i = 0; i < 8; ++i) {
    float* orow =
        out + ((size_t)b * D_ + o0 + ty * 8 + i) * S_ + s0 + tx * 8;
    float4 v0, v1;
    v0.x = fmaxf(acc[i][0], 0.f); v0.y = fmaxf(acc[i][1], 0.f);
    v0.z = fmaxf(acc[i][2], 0.f); v0.w = fmaxf(acc[i][3], 0.f);
    v1.x = fmaxf(acc[i][4], 0.f); v1.y = fmaxf(acc[i][5], 0.f);
    v1.z = fmaxf(acc[i][6], 0.f); v1.w = fmaxf(acc[i][7], 0.f);
    *(float4*)(orow + 0) = v0;
    *(float4*)(orow + 4) = v1;
  }
}

// ---------------------------------------------------------------------------
// Workspace layout (round-14):
//  [ 0, 8M) Xbf | [ 8,16M) (free, was Kbf) | [16,18M) WkT | [18,20M) WGbf
//  [20,22M) WfT | [22M,+512K) part | +512K partG | [23M,+128K) partB
//  +128K biasK(4K) | +256K ropeT | +512K scores | +768K mS
// Pipeline (4 launches):
//  prep -> fusion GEMM(WfT = WkT@W_G) + q0/biasK/rope/Xcast extras
//       -> K GEMM with fused RoPE+score+softmax-partial epilogue -> conv.
// ---------------------------------------------------------------------------
extern "C" void kernel_launch(void* const* d_in, const int* in_sizes, int n_in,
                              void* d_out, int out_size, void* d_ws,
                              size_t ws_size, hipStream_t stream) {
  const float* x    = (const float*)d_in[0];
  const int*   mask = (const int*)d_in[1];
  const float* W_G  = (const float*)d_in[2];
  const float* b_G  = (const float*)d_in[3];
  const float* Wq   = (const float*)d_in[4];
  const float* bq   = (const float*)d_in[5];
  const float* Wk   = (const float*)d_in[6];
  const float* bk   = (const float*)d_in[7];
  const float* cw   = (const float*)d_in[8];
  const float* cb   = (const float*)d_in[9];
  float* out = (float*)d_out;

  char* ws = (char*)d_ws;
  unsigned short* Xbf  = (unsigned short*)(ws);
  unsigned short* WkT  = (unsigned short*)(ws + (16u << 20));
  unsigned short* WGbf = (unsigned short*)(ws + (18u << 20));
  unsigned short* WfT  = (unsigned short*)(ws + (20u << 20));
  float* part   = (float*)(ws + (22u << 20));
  float* partG  = (float*)(ws + (22u << 20) + (512u << 10));
  float* partB  = (float*)(ws + (23u << 20));
  float* biasK  = (float*)(ws + (23u << 20) + (128u << 10));
  float* ropeT  = (float*)(ws + (23u << 20) + (256u << 10));
  float* scores = (float*)(ws + (23u << 20) + (512u << 10));
  float* mS     = (float*)(ws + (23u << 20) + (768u << 10));

  // 1) W_G cast, WkT transpose, fp32 g0/biasK partials (fusion-launch inputs)
  prep_kernel<<<1792, 256, 0, stream>>>(x, W_G, Wk, b_G, WGbf, WkT,
                                        partG, partB);
  // 2) WfT = WkT @ W_G (128 GEMM blocks) + extras: q0 partials (128),
  //    biasK combine (4), RoPE table (128), X bf16 cast (2048)
  gemm_bf16<<<2436, 256, 0, stream>>>(WkT, WGbf, nullptr, WfT, 4, 128,
                                      Wq, part, partG, b_G, partB, bk, biasK,
                                      x, Xbf, ropeT,
                                      nullptr, nullptr, nullptr, nullptr);
  // 3) K = Xbf @ Wf + biasK, fused into scores + per-chunk softmax partials
  gemm_bf16<<<512, 256, 0, stream>>>(Xbf, WfT, biasK, nullptr, 6, 512,
                                     nullptr, part, nullptr, nullptr,
                                     nullptr, nullptr, nullptr,
                                     nullptr, nullptr, ropeT,
                                     bq, mask, scores, mS);
  // 4) softmax combine + conv1d + bias + ReLU
  conv_norm_relu_kernel<<<dim3(8, B_, 8), 256, 0, stream>>>(
      scores, mS, cw, cb, out);
}

// Round 3
// 150.686 us; speedup vs baseline: 1.0152x; 1.0152x over previous
//
#include <hip/hip_runtime.h>
#include <math.h>

// Problem constants
#define B_  4
#define S_  1024
#define D_  1024
#define H_  16
#define DK_ 64
#define M_  (B_ * S_)   // 4096 rows for the K GEMM

typedef __bf16 bf16x8 __attribute__((ext_vector_type(8)));
typedef float  f32x4  __attribute__((ext_vector_type(4)));

// ---- bf16 helpers (RNE) ----------------------------------------------------
__device__ __forceinline__ unsigned short f2bf(float f) {
  unsigned u = __builtin_bit_cast(unsigned, f);
  u = (u + 0x7FFFu + ((u >> 16) & 1u)) >> 16;
  return (unsigned short)u;
}
__device__ __forceinline__ float bf2f(unsigned short h) {
  unsigned u = ((unsigned)h) << 16;
  return __builtin_bit_cast(float, u);
}

// async global->LDS, 16 B per lane; LDS dest = wave-uniform base + lane*16
__device__ __forceinline__ void gl_lds16(const void* g, void* lds) {
  __builtin_amdgcn_global_load_lds(
      (const __attribute__((address_space(1))) unsigned int*)(unsigned long long)g,
      (__attribute__((address_space(3))) unsigned int*)(unsigned int)(unsigned long long)lds,
      16, 0, 0);
}

// ---------------------------------------------------------------------------
// PREP (round-14 verbatim): only what the fusion GEMM launch reads.
//  blocks [   0, 512): W_G fp32 -> bf16 cast (row-major, BT operand of fusion)
//  blocks [ 512,1536): Wk transpose+cast -> WkT bf16 [n][mid]
//  blocks [1536,1664): g0 partials (fp32)
//  blocks [1664,1792): biasK partials
// ---------------------------------------------------------------------------
__global__ __launch_bounds__(256) void prep_kernel(
    const float* __restrict__ X, const float* __restrict__ W_G,
    const float* __restrict__ Wk, const float* __restrict__ bG,
    unsigned short* __restrict__ WGbf, unsigned short* __restrict__ WkT,
    float* __restrict__ partG, float* __restrict__ partB) {
  __shared__ float tle[32][33];
  __shared__ float gs2[4][32];
  __shared__ float bgs[32];
  const int blk = blockIdx.x;
  const int tid = threadIdx.x;

  if (blk < 512) {
    // W_G plain cast (1M elems over 512 blocks)
    const int i = (blk * 256 + tid) * 2;
    const float4 v0 = ((const float4*)W_G)[i];
    const float4 v1 = ((const float4*)W_G)[i + 1];
    ushort4 h0, h1;
    h0.x = f2bf(v0.x); h0.y = f2bf(v0.y); h0.z = f2bf(v0.z); h0.w = f2bf(v0.w);
    h1.x = f2bf(v1.x); h1.y = f2bf(v1.y); h1.z = f2bf(v1.z); h1.w = f2bf(v1.w);
    ((ushort4*)WGbf)[i] = h0;
    ((ushort4*)WGbf)[i + 1] = h1;
  } else if (blk < 1536) {
    // Wk transpose+cast (32x32 tiles, LDS bounce)
    const int t = blk - 512;
    const int k0 = (t & 31) * 32;
    const int n0 = (t >> 5) * 32;
    const int tx = tid & 31;
    const int ty = tid >> 5;  // 0..7
#pragma unroll
    for (int r = 0; r < 32; r += 8)
      tle[ty + r][tx] = Wk[(size_t)(k0 + ty + r) * 1024 + n0 + tx];
    __syncthreads();
#pragma unroll
    for (int r = 0; r < 32; r += 8)
      WkT[(size_t)(n0 + ty + r) * 1024 + k0 + tx] = f2bf(tle[tx][ty + r]);
  } else if (blk < 1664) {
    // g0 partials: fp32, reads X row 0 of each batch + a W_G slab
    const int bl = blk - 1536;       // 0..127
    const int sg = bl >> 2;          // k-slab 0..31
    const int mg = bl & 3;           // mid group 0..3
    if (tid < 128) {
      const int b = tid >> 5, kk = tid & 31;
      gs2[b][kk] = X[(size_t)b * S_ * D_ + sg * 32 + kk];
    }
    __syncthreads();
    const int mid = mg * 256 + tid;
    float a0 = 0.f, a1 = 0.f, a2 = 0.f, a3 = 0.f;
#pragma unroll
    for (int kk = 0; kk < 32; ++kk) {
      const float w = W_G[(size_t)(sg * 32 + kk) * 1024 + mid];
      a0 = fmaf(gs2[0][kk], w, a0);
      a1 = fmaf(gs2[1][kk], w, a1);
      a2 = fmaf(gs2[2][kk], w, a2);
      a3 = fmaf(gs2[3][kk], w, a3);
    }
    partG[(size_t)(sg * 4 + 0) * 1024 + mid] = a0;
    partG[(size_t)(sg * 4 + 1) * 1024 + mid] = a1;
    partG[(size_t)(sg * 4 + 2) * 1024 + mid] = a2;
    partG[(size_t)(sg * 4 + 3) * 1024 + mid] = a3;
  } else {
    // biasK partials: partB[sl][n] = sum_{mid in slab} b_G[mid]*Wk[mid][n]
    const int bl = blk - 1664;       // 0..127
    const int sl = bl >> 2;          // mid-slab 0..31
    const int ng = bl & 3;
    if (tid < 32) bgs[tid] = bG[sl * 32 + tid];
    __syncthreads();
    const int n = ng * 256 + tid;
    float a = 0.f;
#pragma unroll
    for (int kk = 0; kk < 32; ++kk)
      a = fmaf(bgs[kk], Wk[(size_t)(sl * 32 + kk) * 1024 + n], a);
    partB[(size_t)sl * 1024 + n] = a;
  }
}

// ---------------------------------------------------------------------------
// bf16 MFMA GEMM — round-14 verbatim (proven inner loop + score-mode epilogue
// + fusion-launch extra blocks).
// ---------------------------------------------------------------------------
#define GM 64
#define GN 128

__global__ __launch_bounds__(256) void gemm_bf16(
    const unsigned short* __restrict__ A, const unsigned short* __restrict__ BT,
    const float* __restrict__ bias, unsigned short* __restrict__ C,
    const int mShift, const int nGemmBlocks,
    const float* __restrict__ Wq, float* __restrict__ part,
    const float* __restrict__ partG, const float* __restrict__ bG,
    const float* __restrict__ partB, const float* __restrict__ bk,
    float* __restrict__ biasK,
    const float* __restrict__ X, unsigned short* __restrict__ Xbf,
    float* __restrict__ tab,
    const float* __restrict__ bq, const int* __restrict__ mask,
    float* __restrict__ scores, float* __restrict__ mS) {
  __shared__ __align__(16) unsigned short As[2][GM * 32];   // 8 KB
  __shared__ __align__(16) unsigned short Bs[2][GN * 32];   // 16 KB
  __shared__ float gs[4][32];
  __shared__ float q0s[128];
  __shared__ float sc[64][9];   // [s_loc][wv*2+ni], +1 pad col

  const int flat = blockIdx.x;
  const int tid  = threadIdx.x;

  if (flat >= nGemmBlocks) {
    const int eb = flat - nGemmBlocks;
    if (eb < 128) {
      // ---- fused q0 partial: part[(slab*4+b)*D+n] = sum_k g0[b,k]*Wq[k,n]
      const int slab = eb >> 2;            // 0..31 (k-slab of q0 GEMV)
      const int n = (eb & 3) * 256 + tid;  // 0..1023
      if (tid < 128) {
        const int b = tid >> 5, kk = tid & 31;
        float v = bG[slab * 32 + kk];
        const float* pg = partG + (size_t)b * 1024 + slab * 32 + kk;
#pragma unroll
        for (int sg = 0; sg < 32; ++sg) v += pg[(size_t)sg * 4096];
        gs[b][kk] = v;
      }
      __syncthreads();
      float a0 = 0.f, a1 = 0.f, a2 = 0.f, a3 = 0.f;
#pragma unroll
      for (int kk = 0; kk < 32; ++kk) {
        const float w = Wq[(size_t)(slab * 32 + kk) * D_ + n];
        a0 = fmaf(gs[0][kk], w, a0);
        a1 = fmaf(gs[1][kk], w, a1);
        a2 = fmaf(gs[2][kk], w, a2);
        a3 = fmaf(gs[3][kk], w, a3);
      }
      part[(size_t)(slab * 4 + 0) * D_ + n] = a0;
      part[(size_t)(slab * 4 + 1) * D_ + n] = a1;
      part[(size_t)(slab * 4 + 2) * D_ + n] = a2;
      part[(size_t)(slab * 4 + 3) * D_ + n] = a3;
    } else if (eb < 132) {
      // ---- biasK combine: biasK[n] = bk[n] + sum_sl partB[sl][n]
      const int n = (eb - 128) * 256 + tid;
      float v = bk[n];
#pragma unroll
      for (int sl = 0; sl < 32; ++sl) v += partB[(size_t)sl * 1024 + n];
      biasK[n] = v;
    } else if (eb < 260) {
      // ---- RoPE table: tab[s*64+2j]=cos(s*inv_j), +1 = sin
      const int idx = (eb - 132) * 256 + tid;
      const int s = idx >> 5, j = idx & 31;
      const float inv = (float)exp(-(double)j * (9.210340371976182736 / 32.0));
      float sn, c;
      sincosf((float)s * inv, &sn, &c);
      tab[(size_t)s * 64 + 2 * j] = c;
      tab[(size_t)s * 64 + 2 * j + 1] = sn;
    } else {
      // ---- X fp32 -> bf16 cast (consumer is the NEXT launch)
      const int i = ((eb - 260) * 256 + tid) * 2;  // float4 index
      const float4 v0 = ((const float4*)X)[i];
      const float4 v1 = ((const float4*)X)[i + 1];
      ushort4 h0, h1;
      h0.x = f2bf(v0.x); h0.y = f2bf(v0.y); h0.z = f2bf(v0.z); h0.w = f2bf(v0.w);
      h1.x = f2bf(v1.x); h1.y = f2bf(v1.y); h1.z = f2bf(v1.z); h1.w = f2bf(v1.w);
      ((ushort4*)Xbf)[i] = h0;
      ((ushort4*)Xbf)[i + 1] = h1;
    }
    return;
  }

  // ---- GEMM path ----
  const int bx = flat >> mShift;               // N tiles: 8
  const int by = flat & ((1 << mShift) - 1);   // M tiles: 16 or 64
  const int wv   = tid >> 6;
  const int lane = tid & 63;
  const int m0 = by * GM;
  const int n0 = bx * GN;

  // score mode: stage q0 (both heads of this block) into LDS before the loop;
  // covered by the loop's first __syncthreads.
  if (scores && tid < 128) {
    const int nq = n0 + tid;
    float v = bq[nq];
#pragma unroll
    for (int sl2 = 0; sl2 < 32; ++sl2)
      v += part[(size_t)(sl2 * 4 + (m0 >> 10)) * D_ + nq];
    q0s[tid] = v;
  }

  const int colOff = (lane & 3) * 8;
  const size_t aOff  = (size_t)(m0 + 16 * wv + (lane >> 2)) * 1024 + colOff;
  const size_t bOff0 = (size_t)(n0 + 32 * wv + (lane >> 2)) * 1024 + colOff;
  const size_t bOff1 = bOff0 + (size_t)16 * 1024;

  const int l15  = lane & 15;
  const int quad = lane >> 4;

  f32x4 acc[4][2];
#pragma unroll
  for (int i = 0; i < 4; ++i)
#pragma unroll
    for (int j = 0; j < 2; ++j) acc[i][j] = (f32x4){0.f, 0.f, 0.f, 0.f};

#pragma unroll 1
  for (int k0 = 0; k0 < 1024; k0 += 64) {
    __syncthreads();                      // prior LDS reads done
#pragma unroll
    for (int ks = 0; ks < 2; ++ks) {
      gl_lds16(A  + aOff  + k0 + ks * 32, &As[ks][wv * 512]);
      gl_lds16(BT + bOff0 + k0 + ks * 32, &Bs[ks][wv * 1024]);
      gl_lds16(BT + bOff1 + k0 + ks * 32, &Bs[ks][wv * 1024 + 512]);
    }
    __syncthreads();                      // vmcnt drain: LDS writes visible

#pragma unroll
    for (int ks = 0; ks < 2; ++ks) {
      bf16x8 af[4], bfr[2];
#pragma unroll
      for (int mi = 0; mi < 4; ++mi)
        af[mi] = *(const bf16x8*)(&As[ks][(mi * 16 + l15) * 32 + quad * 8]);
#pragma unroll
      for (int ni = 0; ni < 2; ++ni)
        bfr[ni] =
            *(const bf16x8*)(&Bs[ks][(wv * 32 + ni * 16 + l15) * 32 + quad * 8]);
#pragma unroll
      for (int mi = 0; mi < 4; ++mi)
#pragma unroll
        for (int ni = 0; ni < 2; ++ni)
          acc[mi][ni] = __builtin_amdgcn_mfma_f32_16x16x32_bf16(
              af[mi], bfr[ni], acc[mi][ni], 0, 0, 0);
    }
  }

  if (scores) {
    // ---- fused RoPE + q0-dot + per-chunk softmax-partial epilogue ----
    const int b_i   = m0 >> 10;
    const int sbase = m0 & 1023;
#pragma unroll
    for (int ni = 0; ni < 2; ++ni) {
      const int n_loc = wv * 32 + ni * 16 + l15;  // 0..127
      const float bv  = bias[n0 + n_loc];
      const float q0a = q0s[n_loc];
      const float q0b = q0s[n_loc ^ 1];
      const float sq  = (n_loc & 1) ? -q0b : q0b;
      const int j2    = (n_loc & 63) & ~1;
#pragma unroll
      for (int mi = 0; mi < 4; ++mi) {
#pragma unroll
        for (int r = 0; r < 4; ++r) {
          const int s_loc = mi * 16 + quad * 4 + r;
          const float2 cs =
              *(const float2*)(tab + (size_t)(sbase + s_loc) * 64 + j2);
          const float coef = q0a * cs.x + sq * cs.y;
          float v = (acc[mi][ni][r] + bv) * coef;
          v += __shfl_xor(v, 1);
          v += __shfl_xor(v, 2);
          v += __shfl_xor(v, 4);
          v += __shfl_xor(v, 8);   // sum over 16 lanes (same quad = same s)
          if (l15 == 0) sc[s_loc][wv * 2 + ni] = v;
        }
      }
    }
    __syncthreads();
    if (tid < 128) {
      const int h_loc = tid >> 6;   // wave0 = head0, wave1 = head1
      const int s_loc = tid & 63;
      const float* row = sc[s_loc];
      float dot = (row[h_loc * 4 + 0] + row[h_loc * 4 + 1]) +
                  (row[h_loc * 4 + 2] + row[h_loc * 4 + 3]);
      dot *= 0.125f;  // 1/sqrt(64)
      const int s = sbase + s_loc;
      if (mask[b_i * S_ + s] == 0) dot = -1e9f;
      const int bh = b_i * H_ + (bx * 2 + h_loc);
      scores[(size_t)bh * S_ + s] = dot;
      float mx = dot;
#pragma unroll
      for (int off = 16; off >= 1; off >>= 1)
        mx = fmaxf(mx, __shfl_xor(mx, off, 32));
      float e = expf(dot - mx);
#pragma unroll
      for (int off = 16; off >= 1; off >>= 1) e += __shfl_xor(e, off, 32);
      if ((s_loc & 31) == 0) {
        const int ch = ((by & 15) << 1) + (s_loc >> 5);
        mS[((size_t)bh * 32 + ch) * 2 + 0] = mx;
        mS[((size_t)bh * 32 + ch) * 2 + 1] = e;
      }
    }
    return;
  }

  // epilogue: C/D layout col = lane&15, row = quad*4 + r (m89/m91 verified)
#pragma unroll
  for (int ni = 0; ni < 2; ++ni) {
    const int n = n0 + wv * 32 + ni * 16 + l15;
    const float bv = bias ? bias[n] : 0.f;
#pragma unroll
    for (int mi = 0; mi < 4; ++mi) {
#pragma unroll
      for (int r = 0; r < 4; ++r) {
        const int m = m0 + mi * 16 + quad * 4 + r;
        C[(size_t)m * 1024 + n] = f2bf(acc[mi][ni][r] + bv);
      }
    }
  }
}

// ---------------------------------------------------------------------------
// Conv1d (16->1024, k=3, pad=1) + bias + ReLU — ROUND-15 REWRITE (v4).
// v3 was latency-bound: 256 blocks = 1 block/CU = 1 wave/SIMD, so every
// ds_read->FMA dependency ate its full ~120cy latency (VALUBusy 11.5%,
// Occupancy 9.6%, 48us for a ~3us-roofline kernel). v4:
//  * tile 64o x 128s per block -> grid 8x4x16 = 512 blocks = 2/CU = 8
//    waves/CU (2/SIMD), LDS ~26 KB/block.
//  * thread = 4o x 8s register tile: per c, 2xb128+1xb64 (p window, swizzled)
//    + 3xb128 (w, 16-lane broadcast) feed 96 FMA.
//  * pm column swizzle phys = 12*(col>>3)+(col&7): lane stride becomes 12
//    floats -> 8 distinct bank groups -> 2-way aliasing (free, m136); v3's
//    8-float stride was a 4-way conflict (1.59M SQ_LDS_BANK_CONFLICT).
// Same (c-major, t-minor, bias-first) summation order -> bitwise-identical
// output to v3.
// ---------------------------------------------------------------------------
__global__ __launch_bounds__(256) void conv_norm_relu_kernel(
    const float* __restrict__ scores, const float* __restrict__ mS,
    const float* __restrict__ cw, const float* __restrict__ cb,
    float* __restrict__ out) {
  const int b  = blockIdx.y;
  const int s0 = blockIdx.x * 128;
  const int o0 = blockIdx.z * 64;
  const int tid = threadIdx.x;
  const int tx = tid & 15;   // s group: 8 consecutive s at s0 + tx*8
  const int ty = tid >> 4;   // o group: 4 consecutive o at o0 + ty*4

  __shared__ float msh[16], ish[16];
  __shared__ __align__(16) float wT[48][68];   // [ct][o-local], 13 KB
  __shared__ float cbs[64];
  __shared__ __align__(16) float pm[16][196];  // swizzled p, 12.5 KB

  // softmax combine (proven)
  if (tid < 16) {
    const int bh = b * H_ + tid;
    float m = -3e38f;
#pragma unroll
    for (int c = 0; c < 32; ++c)
      m = fmaxf(m, mS[(size_t)(bh * 32 + c) * 2]);
    float S = 0.f;
#pragma unroll
    for (int c = 0; c < 32; ++c)
      S += mS[(size_t)(bh * 32 + c) * 2 + 1] *
           expf(mS[(size_t)(bh * 32 + c) * 2] - m);
    msh[tid] = m;
    ish[tid] = 1.f / S;
  }
  // weight tile, transposed: wT[ct][ol] = cw[(o0+ol)*48 + ct]
  for (int i = tid; i < 64 * 48; i += 256) {
    const int ol = i / 48, ct = i % 48;
    wT[ct][ol] = cw[(size_t)(o0 + ol) * 48 + ct];
  }
  if (tid < 64) cbs[tid] = cb[o0 + tid];
  __syncthreads();  // msh/ish ready

  // p halo, swizzled: logical col in [0,130) maps to phys 12*(col>>3)+(col&7)
  for (int i = tid; i < 16 * 130; i += 256) {
    const int c = i / 130, col = i % 130;
    const int gs = s0 - 1 + col;
    pm[c][12 * (col >> 3) + (col & 7)] =
        (gs >= 0 && gs < S_)
            ? expf(scores[(size_t)(b * H_ + c) * S_ + gs] - msh[c]) * ish[c]
            : 0.f;
  }
  __syncthreads();

  float acc[4][8];
#pragma unroll
  for (int i = 0; i < 4; ++i) {
    const float cv = cbs[ty * 4 + i];
#pragma unroll
    for (int j = 0; j < 8; ++j) acc[i][j] = cv;
  }

#pragma unroll
  for (int c = 0; c < 16; ++c) {
    // pl[m] = p(s0 + tx*8 + m - 1 + 1) ... logical cols tx*8 .. tx*8+9
    float pl[10];
    const float* base = &pm[c][12 * tx];
    *(float4*)(pl + 0) = *(const float4*)(base + 0);
    *(float4*)(pl + 4) = *(const float4*)(base + 4);
    *(float2*)(pl + 8) = *(const float2*)(&pm[c][12 * (tx + 1)]);
#pragma unroll
    for (int t = 0; t < 3; ++t) {
      float w[4];
      *(float4*)w = *(const float4*)&wT[c * 3 + t][ty * 4];
#pragma unroll
      for (int i = 0; i < 4; ++i)
#pragma unroll
        for (int j = 0; j < 8; ++j)
          acc[i][j] = fmaf(pl[j + t], w[i], acc[i][j]);
    }
  }

#pragma unroll
  for (int i = 0; i < 4; ++i) {
    float* orow =
        out + ((size_t)b * D_ + o0 + ty * 4 + i) * S_ + s0 + tx * 8;
    float4 v0, v1;
    v0.x = fmaxf(acc[i][0], 0.f); v0.y = fmaxf(acc[i][1], 0.f);
    v0.z = fmaxf(acc[i][2], 0.f); v0.w = fmaxf(acc[i][3], 0.f);
    v1.x = fmaxf(acc[i][4], 0.f); v1.y = fmaxf(acc[i][5], 0.f);
    v1.z = fmaxf(acc[i][6], 0.f); v1.w = fmaxf(acc[i][7], 0.f);
    *(float4*)(orow + 0) = v0;
    *(float4*)(orow + 4) = v1;
  }
}

// ---------------------------------------------------------------------------
// Workspace layout (round-14):
//  [ 0, 8M) Xbf | [16,18M) WkT | [18,20M) WGbf | [20,22M) WfT
//  [22M,+512K) part | +512K partG | [23M,+128K) partB | +128K biasK(4K)
//  +256K ropeT | +512K scores | +768K mS
// Pipeline (4 launches):
//  prep -> fusion GEMM(WfT = WkT@W_G) + q0/biasK/rope/Xcast extras
//       -> K GEMM with fused RoPE+score+softmax-partial epilogue -> conv.
// ---------------------------------------------------------------------------
extern "C" void kernel_launch(void* const* d_in, const int* in_sizes, int n_in,
                              void* d_out, int out_size, void* d_ws,
                              size_t ws_size, hipStream_t stream) {
  const float* x    = (const float*)d_in[0];
  const int*   mask = (const int*)d_in[1];
  const float* W_G  = (const float*)d_in[2];
  const float* b_G  = (const float*)d_in[3];
  const float* Wq   = (const float*)d_in[4];
  const float* bq   = (const float*)d_in[5];
  const float* Wk   = (const float*)d_in[6];
  const float* bk   = (const float*)d_in[7];
  const float* cw   = (const float*)d_in[8];
  const float* cb   = (const float*)d_in[9];
  float* out = (float*)d_out;

  char* ws = (char*)d_ws;
  unsigned short* Xbf  = (unsigned short*)(ws);
  unsigned short* WkT  = (unsigned short*)(ws + (16u << 20));
  unsigned short* WGbf = (unsigned short*)(ws + (18u << 20));
  unsigned short* WfT  = (unsigned short*)(ws + (20u << 20));
  float* part   = (float*)(ws + (22u << 20));
  float* partG  = (float*)(ws + (22u << 20) + (512u << 10));
  float* partB  = (float*)(ws + (23u << 20));
  float* biasK  = (float*)(ws + (23u << 20) + (128u << 10));
  float* ropeT  = (float*)(ws + (23u << 20) + (256u << 10));
  float* scores = (float*)(ws + (23u << 20) + (512u << 10));
  float* mS     = (float*)(ws + (23u << 20) + (768u << 10));

  // 1) W_G cast, WkT transpose, fp32 g0/biasK partials (fusion-launch inputs)
  prep_kernel<<<1792, 256, 0, stream>>>(x, W_G, Wk, b_G, WGbf, WkT,
                                        partG, partB);
  // 2) WfT = WkT @ W_G (128 GEMM blocks) + extras: q0 partials (128),
  //    biasK combine (4), RoPE table (128), X bf16 cast (2048)
  gemm_bf16<<<2436, 256, 0, stream>>>(WkT, WGbf, nullptr, WfT, 4, 128,
                                      Wq, part, partG, b_G, partB, bk, biasK,
                                      x, Xbf, ropeT,
                                      nullptr, nullptr, nullptr, nullptr);
  // 3) K = Xbf @ Wf + biasK, fused into scores + per-chunk softmax partials
  gemm_bf16<<<512, 256, 0, stream>>>(Xbf, WfT, biasK, nullptr, 6, 512,
                                     nullptr, part, nullptr, nullptr,
                                     nullptr, nullptr, nullptr,
                                     nullptr, nullptr, ropeT,
                                     bq, mask, scores, mS);
  // 4) softmax combine + conv1d + bias + ReLU (512 blocks, 2/CU)
  conv_norm_relu_kernel<<<dim3(8, B_, 16), 256, 0, stream>>>(
      scores, mS, cw, cb, out);
}

// Round 4
// 140.309 us; speedup vs baseline: 1.0903x; 1.0740x over previous
//
#include <hip/hip_runtime.h>
#include <math.h>

// Problem constants
#define B_  4
#define S_  1024
#define D_  1024
#define H_  16
#define DK_ 64
#define M_  (B_ * S_)   // 4096 rows for the K GEMM

typedef __bf16 bf16x8 __attribute__((ext_vector_type(8)));
typedef float  f32x4  __attribute__((ext_vector_type(4)));

// ---- bf16 helpers (RNE) ----------------------------------------------------
__device__ __forceinline__ unsigned short f2bf(float f) {
  unsigned u = __builtin_bit_cast(unsigned, f);
  u = (u + 0x7FFFu + ((u >> 16) & 1u)) >> 16;
  return (unsigned short)u;
}
__device__ __forceinline__ float bf2f(unsigned short h) {
  unsigned u = ((unsigned)h) << 16;
  return __builtin_bit_cast(float, u);
}

// async global->LDS, 16 B per lane; LDS dest = wave-uniform base + lane*16
__device__ __forceinline__ void gl_lds16(const void* g, void* lds) {
  __builtin_amdgcn_global_load_lds(
      (const __attribute__((address_space(1))) unsigned int*)(unsigned long long)g,
      (__attribute__((address_space(3))) unsigned int*)(unsigned int)(unsigned long long)lds,
      16, 0, 0);
}

// ---------------------------------------------------------------------------
// PREP (round-14 verbatim): only what the fusion GEMM launch reads.
//  blocks [   0, 512): W_G fp32 -> bf16 cast (row-major, BT operand of fusion)
//  blocks [ 512,1536): Wk transpose+cast -> WkT bf16 [n][mid]
//  blocks [1536,1664): g0 partials (fp32)
//  blocks [1664,1792): biasK partials
// ---------------------------------------------------------------------------
__global__ __launch_bounds__(256) void prep_kernel(
    const float* __restrict__ X, const float* __restrict__ W_G,
    const float* __restrict__ Wk, const float* __restrict__ bG,
    unsigned short* __restrict__ WGbf, unsigned short* __restrict__ WkT,
    float* __restrict__ partG, float* __restrict__ partB) {
  __shared__ float tle[32][33];
  __shared__ float gs2[4][32];
  __shared__ float bgs[32];
  const int blk = blockIdx.x;
  const int tid = threadIdx.x;

  if (blk < 512) {
    // W_G plain cast (1M elems over 512 blocks)
    const int i = (blk * 256 + tid) * 2;
    const float4 v0 = ((const float4*)W_G)[i];
    const float4 v1 = ((const float4*)W_G)[i + 1];
    ushort4 h0, h1;
    h0.x = f2bf(v0.x); h0.y = f2bf(v0.y); h0.z = f2bf(v0.z); h0.w = f2bf(v0.w);
    h1.x = f2bf(v1.x); h1.y = f2bf(v1.y); h1.z = f2bf(v1.z); h1.w = f2bf(v1.w);
    ((ushort4*)WGbf)[i] = h0;
    ((ushort4*)WGbf)[i + 1] = h1;
  } else if (blk < 1536) {
    // Wk transpose+cast (32x32 tiles, LDS bounce)
    const int t = blk - 512;
    const int k0 = (t & 31) * 32;
    const int n0 = (t >> 5) * 32;
    const int tx = tid & 31;
    const int ty = tid >> 5;  // 0..7
#pragma unroll
    for (int r = 0; r < 32; r += 8)
      tle[ty + r][tx] = Wk[(size_t)(k0 + ty + r) * 1024 + n0 + tx];
    __syncthreads();
#pragma unroll
    for (int r = 0; r < 32; r += 8)
      WkT[(size_t)(n0 + ty + r) * 1024 + k0 + tx] = f2bf(tle[tx][ty + r]);
  } else if (blk < 1664) {
    // g0 partials: fp32, reads X row 0 of each batch + a W_G slab
    const int bl = blk - 1536;       // 0..127
    const int sg = bl >> 2;          // k-slab 0..31
    const int mg = bl & 3;           // mid group 0..3
    if (tid < 128) {
      const int b = tid >> 5, kk = tid & 31;
      gs2[b][kk] = X[(size_t)b * S_ * D_ + sg * 32 + kk];
    }
    __syncthreads();
    const int mid = mg * 256 + tid;
    float a0 = 0.f, a1 = 0.f, a2 = 0.f, a3 = 0.f;
#pragma unroll
    for (int kk = 0; kk < 32; ++kk) {
      const float w = W_G[(size_t)(sg * 32 + kk) * 1024 + mid];
      a0 = fmaf(gs2[0][kk], w, a0);
      a1 = fmaf(gs2[1][kk], w, a1);
      a2 = fmaf(gs2[2][kk], w, a2);
      a3 = fmaf(gs2[3][kk], w, a3);
    }
    partG[(size_t)(sg * 4 + 0) * 1024 + mid] = a0;
    partG[(size_t)(sg * 4 + 1) * 1024 + mid] = a1;
    partG[(size_t)(sg * 4 + 2) * 1024 + mid] = a2;
    partG[(size_t)(sg * 4 + 3) * 1024 + mid] = a3;
  } else {
    // biasK partials: partB[sl][n] = sum_{mid in slab} b_G[mid]*Wk[mid][n]
    const int bl = blk - 1664;       // 0..127
    const int sl = bl >> 2;          // mid-slab 0..31
    const int ng = bl & 3;
    if (tid < 32) bgs[tid] = bG[sl * 32 + tid];
    __syncthreads();
    const int n = ng * 256 + tid;
    float a = 0.f;
#pragma unroll
    for (int kk = 0; kk < 32; ++kk)
      a = fmaf(bgs[kk], Wk[(size_t)(sl * 32 + kk) * 1024 + n], a);
    partB[(size_t)sl * 1024 + n] = a;
  }
}

// ---------------------------------------------------------------------------
// bf16 MFMA GEMM — ROUND-16: double-buffered K-loop with COUNTED vmcnt
// (T3/T4-minimal). Old loop serially exposed the full global->LDS round trip
// every K-iteration (sync; stage; sync[vmcnt(0) drain]; compute). New loop:
//   prologue STAGE(tile0)
//   iter t: STAGE(tile t+1) -> s_waitcnt vmcnt(6) [tile t's 6 loads done,
//           next 6 stay IN FLIGHT across both barriers] -> raw s_barrier ->
//           sched_barrier(0) -> ds_read+MFMA on buf[t&1] -> raw s_barrier.
// Raw barriers avoid __syncthreads' mandatory vmcnt(0) drain. Buffer-reuse
// hazard (tile t+2 overwrites buf[t&1]) is protected by barrier #2: ds_reads
// are consumed by MFMAs (compiler lgkmcnt) before any wave proceeds.
// FP order identical -> bitwise-same outputs. LDS 24->48 KB (still 3/CU cap).
// ---------------------------------------------------------------------------
#define GM 64
#define GN 128

__global__ __launch_bounds__(256) void gemm_bf16(
    const unsigned short* __restrict__ A, const unsigned short* __restrict__ BT,
    const float* __restrict__ bias, unsigned short* __restrict__ C,
    const int mShift, const int nGemmBlocks,
    const float* __restrict__ Wq, float* __restrict__ part,
    const float* __restrict__ partG, const float* __restrict__ bG,
    const float* __restrict__ partB, const float* __restrict__ bk,
    float* __restrict__ biasK,
    const float* __restrict__ X, unsigned short* __restrict__ Xbf,
    float* __restrict__ tab,
    const float* __restrict__ bq, const int* __restrict__ mask,
    float* __restrict__ scores, float* __restrict__ mS) {
  __shared__ __align__(16) unsigned short As[2][2][GM * 32];   // 16 KB
  __shared__ __align__(16) unsigned short Bs[2][2][GN * 32];   // 32 KB
  __shared__ float gs[4][32];
  __shared__ float q0s[128];
  __shared__ float sc[64][9];   // [s_loc][wv*2+ni], +1 pad col

  const int flat = blockIdx.x;
  const int tid  = threadIdx.x;

  if (flat >= nGemmBlocks) {
    const int eb = flat - nGemmBlocks;
    if (eb < 128) {
      // ---- fused q0 partial: part[(slab*4+b)*D+n] = sum_k g0[b,k]*Wq[k,n]
      const int slab = eb >> 2;            // 0..31 (k-slab of q0 GEMV)
      const int n = (eb & 3) * 256 + tid;  // 0..1023
      if (tid < 128) {
        const int b = tid >> 5, kk = tid & 31;
        float v = bG[slab * 32 + kk];
        const float* pg = partG + (size_t)b * 1024 + slab * 32 + kk;
#pragma unroll
        for (int sg = 0; sg < 32; ++sg) v += pg[(size_t)sg * 4096];
        gs[b][kk] = v;
      }
      __syncthreads();
      float a0 = 0.f, a1 = 0.f, a2 = 0.f, a3 = 0.f;
#pragma unroll
      for (int kk = 0; kk < 32; ++kk) {
        const float w = Wq[(size_t)(slab * 32 + kk) * D_ + n];
        a0 = fmaf(gs[0][kk], w, a0);
        a1 = fmaf(gs[1][kk], w, a1);
        a2 = fmaf(gs[2][kk], w, a2);
        a3 = fmaf(gs[3][kk], w, a3);
      }
      part[(size_t)(slab * 4 + 0) * D_ + n] = a0;
      part[(size_t)(slab * 4 + 1) * D_ + n] = a1;
      part[(size_t)(slab * 4 + 2) * D_ + n] = a2;
      part[(size_t)(slab * 4 + 3) * D_ + n] = a3;
    } else if (eb < 132) {
      // ---- biasK combine: biasK[n] = bk[n] + sum_sl partB[sl][n]
      const int n = (eb - 128) * 256 + tid;
      float v = bk[n];
#pragma unroll
      for (int sl = 0; sl < 32; ++sl) v += partB[(size_t)sl * 1024 + n];
      biasK[n] = v;
    } else if (eb < 260) {
      // ---- RoPE table: tab[s*64+2j]=cos(s*inv_j), +1 = sin
      const int idx = (eb - 132) * 256 + tid;
      const int s = idx >> 5, j = idx & 31;
      const float inv = (float)exp(-(double)j * (9.210340371976182736 / 32.0));
      float sn, c;
      sincosf((float)s * inv, &sn, &c);
      tab[(size_t)s * 64 + 2 * j] = c;
      tab[(size_t)s * 64 + 2 * j + 1] = sn;
    } else {
      // ---- X fp32 -> bf16 cast (consumer is the NEXT launch)
      const int i = ((eb - 260) * 256 + tid) * 2;  // float4 index
      const float4 v0 = ((const float4*)X)[i];
      const float4 v1 = ((const float4*)X)[i + 1];
      ushort4 h0, h1;
      h0.x = f2bf(v0.x); h0.y = f2bf(v0.y); h0.z = f2bf(v0.z); h0.w = f2bf(v0.w);
      h1.x = f2bf(v1.x); h1.y = f2bf(v1.y); h1.z = f2bf(v1.z); h1.w = f2bf(v1.w);
      ((ushort4*)Xbf)[i] = h0;
      ((ushort4*)Xbf)[i + 1] = h1;
    }
    return;
  }

  // ---- GEMM path ----
  const int bx = flat >> mShift;               // N tiles: 8
  const int by = flat & ((1 << mShift) - 1);   // M tiles: 16 or 64
  const int wv   = tid >> 6;
  const int lane = tid & 63;
  const int m0 = by * GM;
  const int n0 = bx * GN;

  // score mode: stage q0 (both heads of this block) into LDS before the loop;
  // all its global loads are consumed (vmcnt-retired) before the K-loop, and
  // q0s is only read in the epilogue (after barriers).
  if (scores && tid < 128) {
    const int nq = n0 + tid;
    float v = bq[nq];
#pragma unroll
    for (int sl2 = 0; sl2 < 32; ++sl2)
      v += part[(size_t)(sl2 * 4 + (m0 >> 10)) * D_ + nq];
    q0s[tid] = v;
  }

  const int colOff = (lane & 3) * 8;
  const size_t aOff  = (size_t)(m0 + 16 * wv + (lane >> 2)) * 1024 + colOff;
  const size_t bOff0 = (size_t)(n0 + 32 * wv + (lane >> 2)) * 1024 + colOff;
  const size_t bOff1 = bOff0 + (size_t)16 * 1024;

  const int l15  = lane & 15;
  const int quad = lane >> 4;

  f32x4 acc[4][2];
#pragma unroll
  for (int i = 0; i < 4; ++i)
#pragma unroll
    for (int j = 0; j < 2; ++j) acc[i][j] = (f32x4){0.f, 0.f, 0.f, 0.f};

  // stage one 64-wide K-tile into LDS buffer bufi (6 loads/thread)
  auto STAGE = [&](int bufi, int kk) {
#pragma unroll
    for (int ks = 0; ks < 2; ++ks) {
      gl_lds16(A  + aOff  + kk + ks * 32, &As[bufi][ks][wv * 512]);
      gl_lds16(BT + bOff0 + kk + ks * 32, &Bs[bufi][ks][wv * 1024]);
      gl_lds16(BT + bOff1 + kk + ks * 32, &Bs[bufi][ks][wv * 1024 + 512]);
    }
  };

  STAGE(0, 0);  // prologue: tile 0 -> buf 0

#pragma unroll 1
  for (int t = 0; t < 16; ++t) {
    const int cur = t & 1;
    if (t < 15) {
      STAGE(cur ^ 1, (t + 1) * 64);   // next tile's 6 loads: stay in flight
      asm volatile("s_waitcnt vmcnt(6)" ::: "memory");  // tile t complete
    } else {
      asm volatile("s_waitcnt vmcnt(0)" ::: "memory");  // last tile complete
    }
    __builtin_amdgcn_s_barrier();        // raw: no vmcnt(0) drain
    __builtin_amdgcn_sched_barrier(0);   // pin ds_reads below the barrier

#pragma unroll
    for (int ks = 0; ks < 2; ++ks) {
      bf16x8 af[4], bfr[2];
#pragma unroll
      for (int mi = 0; mi < 4; ++mi)
        af[mi] = *(const bf16x8*)(&As[cur][ks][(mi * 16 + l15) * 32 + quad * 8]);
#pragma unroll
      for (int ni = 0; ni < 2; ++ni)
        bfr[ni] = *(const bf16x8*)(
            &Bs[cur][ks][(wv * 32 + ni * 16 + l15) * 32 + quad * 8]);
#pragma unroll
      for (int mi = 0; mi < 4; ++mi)
#pragma unroll
        for (int ni = 0; ni < 2; ++ni)
          acc[mi][ni] = __builtin_amdgcn_mfma_f32_16x16x32_bf16(
              af[mi], bfr[ni], acc[mi][ni], 0, 0, 0);
    }
    __builtin_amdgcn_sched_barrier(0);   // keep stage(t+1) from hoisting up
    __builtin_amdgcn_s_barrier();        // buf[cur] fully consumed
  }

  if (scores) {
    // ---- fused RoPE + q0-dot + per-chunk softmax-partial epilogue ----
    const int b_i   = m0 >> 10;
    const int sbase = m0 & 1023;
#pragma unroll
    for (int ni = 0; ni < 2; ++ni) {
      const int n_loc = wv * 32 + ni * 16 + l15;  // 0..127
      const float bv  = bias[n0 + n_loc];
      const float q0a = q0s[n_loc];
      const float q0b = q0s[n_loc ^ 1];
      const float sq  = (n_loc & 1) ? -q0b : q0b;
      const int j2    = (n_loc & 63) & ~1;
#pragma unroll
      for (int mi = 0; mi < 4; ++mi) {
#pragma unroll
        for (int r = 0; r < 4; ++r) {
          const int s_loc = mi * 16 + quad * 4 + r;
          const float2 cs =
              *(const float2*)(tab + (size_t)(sbase + s_loc) * 64 + j2);
          const float coef = q0a * cs.x + sq * cs.y;
          float v = (acc[mi][ni][r] + bv) * coef;
          v += __shfl_xor(v, 1);
          v += __shfl_xor(v, 2);
          v += __shfl_xor(v, 4);
          v += __shfl_xor(v, 8);   // sum over 16 lanes (same quad = same s)
          if (l15 == 0) sc[s_loc][wv * 2 + ni] = v;
        }
      }
    }
    __syncthreads();
    if (tid < 128) {
      const int h_loc = tid >> 6;   // wave0 = head0, wave1 = head1
      const int s_loc = tid & 63;
      const float* row = sc[s_loc];
      float dot = (row[h_loc * 4 + 0] + row[h_loc * 4 + 1]) +
                  (row[h_loc * 4 + 2] + row[h_loc * 4 + 3]);
      dot *= 0.125f;  // 1/sqrt(64)
      const int s = sbase + s_loc;
      if (mask[b_i * S_ + s] == 0) dot = -1e9f;
      const int bh = b_i * H_ + (bx * 2 + h_loc);
      scores[(size_t)bh * S_ + s] = dot;
      float mx = dot;
#pragma unroll
      for (int off = 16; off >= 1; off >>= 1)
        mx = fmaxf(mx, __shfl_xor(mx, off, 32));
      float e = expf(dot - mx);
#pragma unroll
      for (int off = 16; off >= 1; off >>= 1) e += __shfl_xor(e, off, 32);
      if ((s_loc & 31) == 0) {
        const int ch = ((by & 15) << 1) + (s_loc >> 5);
        mS[((size_t)bh * 32 + ch) * 2 + 0] = mx;
        mS[((size_t)bh * 32 + ch) * 2 + 1] = e;
      }
    }
    return;
  }

  // epilogue: C/D layout col = lane&15, row = quad*4 + r (m89/m91 verified)
#pragma unroll
  for (int ni = 0; ni < 2; ++ni) {
    const int n = n0 + wv * 32 + ni * 16 + l15;
    const float bv = bias ? bias[n] : 0.f;
#pragma unroll
    for (int mi = 0; mi < 4; ++mi) {
#pragma unroll
      for (int r = 0; r < 4; ++r) {
        const int m = m0 + mi * 16 + quad * 4 + r;
        C[(size_t)m * 1024 + n] = f2bf(acc[mi][ni][r] + bv);
      }
    }
  }
}

// ---------------------------------------------------------------------------
// Conv1d (16->1024, k=3, pad=1) + bias + ReLU — round-15 v4 verbatim.
// ---------------------------------------------------------------------------
__global__ __launch_bounds__(256) void conv_norm_relu_kernel(
    const float* __restrict__ scores, const float* __restrict__ mS,
    const float* __restrict__ cw, const float* __restrict__ cb,
    float* __restrict__ out) {
  const int b  = blockIdx.y;
  const int s0 = blockIdx.x * 128;
  const int o0 = blockIdx.z * 64;
  const int tid = threadIdx.x;
  const int tx = tid & 15;   // s group: 8 consecutive s at s0 + tx*8
  const int ty = tid >> 4;   // o group: 4 consecutive o at o0 + ty*4

  __shared__ float msh[16], ish[16];
  __shared__ __align__(16) float wT[48][68];   // [ct][o-local], 13 KB
  __shared__ float cbs[64];
  __shared__ __align__(16) float pm[16][196];  // swizzled p, 12.5 KB

  // softmax combine (proven)
  if (tid < 16) {
    const int bh = b * H_ + tid;
    float m = -3e38f;
#pragma unroll
    for (int c = 0; c < 32; ++c)
      m = fmaxf(m, mS[(size_t)(bh * 32 + c) * 2]);
    float S = 0.f;
#pragma unroll
    for (int c = 0; c < 32; ++c)
      S += mS[(size_t)(bh * 32 + c) * 2 + 1] *
           expf(mS[(size_t)(bh * 32 + c) * 2] - m);
    msh[tid] = m;
    ish[tid] = 1.f / S;
  }
  // weight tile, transposed: wT[ct][ol] = cw[(o0+ol)*48 + ct]
  for (int i = tid; i < 64 * 48; i += 256) {
    const int ol = i / 48, ct = i % 48;
    wT[ct][ol] = cw[(size_t)(o0 + ol) * 48 + ct];
  }
  if (tid < 64) cbs[tid] = cb[o0 + tid];
  __syncthreads();  // msh/ish ready

  // p halo, swizzled: logical col in [0,130) maps to phys 12*(col>>3)+(col&7)
  for (int i = tid; i < 16 * 130; i += 256) {
    const int c = i / 130, col = i % 130;
    const int gs = s0 - 1 + col;
    pm[c][12 * (col >> 3) + (col & 7)] =
        (gs >= 0 && gs < S_)
            ? expf(scores[(size_t)(b * H_ + c) * S_ + gs] - msh[c]) * ish[c]
            : 0.f;
  }
  __syncthreads();

  float acc[4][8];
#pragma unroll
  for (int i = 0; i < 4; ++i) {
    const float cv = cbs[ty * 4 + i];
#pragma unroll
    for (int j = 0; j < 8; ++j) acc[i][j] = cv;
  }

#pragma unroll
  for (int c = 0; c < 16; ++c) {
    float pl[10];
    const float* base = &pm[c][12 * tx];
    *(float4*)(pl + 0) = *(const float4*)(base + 0);
    *(float4*)(pl + 4) = *(const float4*)(base + 4);
    *(float2*)(pl + 8) = *(const float2*)(&pm[c][12 * (tx + 1)]);
#pragma unroll
    for (int t = 0; t < 3; ++t) {
      float w[4];
      *(float4*)w = *(const float4*)&wT[c * 3 + t][ty * 4];
#pragma unroll
      for (int i = 0; i < 4; ++i)
#pragma unroll
        for (int j = 0; j < 8; ++j)
          acc[i][j] = fmaf(pl[j + t], w[i], acc[i][j]);
    }
  }

#pragma unroll
  for (int i = 0; i < 4; ++i) {
    float* orow =
        out + ((size_t)b * D_ + o0 + ty * 4 + i) * S_ + s0 + tx * 8;
    float4 v0, v1;
    v0.x = fmaxf(acc[i][0], 0.f); v0.y = fmaxf(acc[i][1], 0.f);
    v0.z = fmaxf(acc[i][2], 0.f); v0.w = fmaxf(acc[i][3], 0.f);
    v1.x = fmaxf(acc[i][4], 0.f); v1.y = fmaxf(acc[i][5], 0.f);
    v1.z = fmaxf(acc[i][6], 0.f); v1.w = fmaxf(acc[i][7], 0.f);
    *(float4*)(orow + 0) = v0;
    *(float4*)(orow + 4) = v1;
  }
}

// ---------------------------------------------------------------------------
// Workspace layout (round-14):
//  [ 0, 8M) Xbf | [16,18M) WkT | [18,20M) WGbf | [20,22M) WfT
//  [22M,+512K) part | +512K partG | [23M,+128K) partB | +128K biasK(4K)
//  +256K ropeT | +512K scores | +768K mS
// Pipeline (4 launches):
//  prep -> fusion GEMM(WfT = WkT@W_G) + q0/biasK/rope/Xcast extras
//       -> K GEMM with fused RoPE+score+softmax-partial epilogue -> conv.
// ---------------------------------------------------------------------------
extern "C" void kernel_launch(void* const* d_in, const int* in_sizes, int n_in,
                              void* d_out, int out_size, void* d_ws,
                              size_t ws_size, hipStream_t stream) {
  const float* x    = (const float*)d_in[0];
  const int*   mask = (const int*)d_in[1];
  const float* W_G  = (const float*)d_in[2];
  const float* b_G  = (const float*)d_in[3];
  const float* Wq   = (const float*)d_in[4];
  const float* bq   = (const float*)d_in[5];
  const float* Wk   = (const float*)d_in[6];
  const float* bk   = (const float*)d_in[7];
  const float* cw   = (const float*)d_in[8];
  const float* cb   = (const float*)d_in[9];
  float* out = (float*)d_out;

  char* ws = (char*)d_ws;
  unsigned short* Xbf  = (unsigned short*)(ws);
  unsigned short* WkT  = (unsigned short*)(ws + (16u << 20));
  unsigned short* WGbf = (unsigned short*)(ws + (18u << 20));
  unsigned short* WfT  = (unsigned short*)(ws + (20u << 20));
  float* part   = (float*)(ws + (22u << 20));
  float* partG  = (float*)(ws + (22u << 20) + (512u << 10));
  float* partB  = (float*)(ws + (23u << 20));
  float* biasK  = (float*)(ws + (23u << 20) + (128u << 10));
  float* ropeT  = (float*)(ws + (23u << 20) + (256u << 10));
  float* scores = (float*)(ws + (23u << 20) + (512u << 10));
  float* mS     = (float*)(ws + (23u << 20) + (768u << 10));

  // 1) W_G cast, WkT transpose, fp32 g0/biasK partials (fusion-launch inputs)
  prep_kernel<<<1792, 256, 0, stream>>>(x, W_G, Wk, b_G, WGbf, WkT,
                                        partG, partB);
  // 2) WfT = WkT @ W_G (128 GEMM blocks) + extras: q0 partials (128),
  //    biasK combine (4), RoPE table (128), X bf16 cast (2048)
  gemm_bf16<<<2436, 256, 0, stream>>>(WkT, WGbf, nullptr, WfT, 4, 128,
                                      Wq, part, partG, b_G, partB, bk, biasK,
                                      x, Xbf, ropeT,
                                      nullptr, nullptr, nullptr, nullptr);
  // 3) K = Xbf @ Wf + biasK, fused into scores + per-chunk softmax partials
  gemm_bf16<<<512, 256, 0, stream>>>(Xbf, WfT, biasK, nullptr, 6, 512,
                                     nullptr, part, nullptr, nullptr,
                                     nullptr, nullptr, nullptr,
                                     nullptr, nullptr, ropeT,
                                     bq, mask, scores, mS);
  // 4) softmax combine + conv1d + bias + ReLU (512 blocks, 2/CU)
  conv_norm_relu_kernel<<<dim3(8, B_, 16), 256, 0, stream>>>(
      scores, mS, cw, cb, out);
}